// Round 3
// baseline (935.946 us; speedup 1.0000x reference)
//
#include <hip/hip_runtime.h>
#include <hip/hip_bf16.h>
#include <hip/hip_cooperative_groups.h>

namespace cg = cooperative_groups;

typedef __hip_bfloat16 bf;
typedef unsigned int u32x4 __attribute__((ext_vector_type(4)));

#define NN   1000
#define DD   100
#define FF   100
#define TIF  512
#define HDD  128
#define EB   256
#define ACAP 96
#define MCAP 192

// output layout (element offsets, float32)
#define O_LAM 0
#define O_Z   100
#define O_B3  1000100
#define O_GAM 1001100
#define O_ETA 1001200
#define O_ZE  1001300
#define O_H   101001300

// dtype-agnostic input load: F32=1 -> buffer is float32, else bf16
__device__ __forceinline__ float ldf(const void* p, int i, int F32){
  return F32 ? ((const float*)p)[i] : __bfloat162float(((const __hip_bfloat16*)p)[i]);
}

// wave-local LDS sync: a wave writes its private LDS region then reads it.
// DS ops are in-order per wave; we just need the compiler not to reorder.
__device__ __forceinline__ void wave_lds_sync(){
  asm volatile("s_waitcnt lgkmcnt(0)" ::: "memory");
  __builtin_amdgcn_wave_barrier();
  __builtin_amdgcn_sched_barrier(0);
}

// half-block (128-thread) reduction; MUST be called by all 256 threads of the block
// (both halves execute identical barrier sequences; red is per-half region)
__device__ __forceinline__ float blk_red_half(float v, volatile float* red, int tx){
#pragma unroll
  for (int o=32;o>0;o>>=1) v += __shfl_down(v,o,64);
  if ((tx&63)==0) red[tx>>6]=v;
  __syncthreads();
  float r = red[0]+red[1];
  __syncthreads();
  return r;
}
// 4-wave (256-thread) block reduction
__device__ __forceinline__ float blk_red4(float v, volatile float* red, int tid){
#pragma unroll
  for (int o=32;o>0;o>>=1) v += __shfl_down(v,o,64);
  if ((tid&63)==0) red[tid>>6]=v;
  __syncthreads();
  float r = red[0]+red[1]+red[2]+red[3];
  __syncthreads();
  return r;
}

// per-wave dtype sniff over first 512 u16 of X: f32 buffer -> ~12.5% exps >= 0xE0
__device__ __forceinline__ int sniffF32(const unsigned short* __restrict__ p, int lane){
  const ushort4* q = (const ushort4*)p;
  ushort4 a = q[lane*2], b = q[lane*2+1];
  int c = 0;
  c += (((a.x>>7)&0xFF)>=0xE0); c += (((a.y>>7)&0xFF)>=0xE0);
  c += (((a.z>>7)&0xFF)>=0xE0); c += (((a.w>>7)&0xFF)>=0xE0);
  c += (((b.x>>7)&0xFF)>=0xE0); c += (((b.y>>7)&0xFF)>=0xE0);
  c += (((b.z>>7)&0xFF)>=0xE0); c += (((b.w>>7)&0xFF)>=0xE0);
#pragma unroll
  for (int o=32;o>0;o>>=1) c += __shfl_xor(c,o,64);
  return c > 8;
}

// zeroing: block zi of nzb handles its chunk of [off, off+cnt) 16B quads (nontemporal)
__device__ __forceinline__ void zero_span(uint4* __restrict__ zb_, long off, long cnt,
                                          int zi, int nzb, int tid, int bdim){
  u32x4* __restrict__ zb = (u32x4*)zb_;
  long per = (cnt + nzb - 1)/nzb;
  long s = (long)zi*per; if (s>cnt) s=cnt;
  long e = s+per; if (e>cnt) e=cnt;
  u32x4 z = (u32x4)(0u,0u,0u,0u);
  for (long i=off+s+tid; i<off+e; i+=bdim) __builtin_nontemporal_store(z, &zb[i]);
}

struct Params {
  const void *A, *masks, *wm, *Wbeta, *img, *Wm1, *bm1, *Wm2, *bm2, *X;
  const void *Wg1, *Wg2, *Wh1, *bh1, *Wh2, *bh2;
  const void *Wmu, *bmu, *Weta, *beta_b, *Wgam, *bgam;
  const int *epoch, *epochs;
  int *a_idx, *a_nnz, *m_idx, *m_cnt, *flag;
  float *a_val, *wpr, *sumsq, *limg;
  float *XW, *H1W, *Hh, *Hn, *HnT, *hw, *Eblk;
  float *out;
  uint4 *zb;
};

// ================= cooperative mega-kernel: 512 blocks x 256 threads =================
// Phase A: K1 (wave units) + zero [0, 6.25M)
// Phase B: K2 rows (half-block units) + zero [6.25M, 12.5M)
// Phase C: K3 rows (half-block units) + zero [12.5M, 18.75M)
// Phase D: K4 tiles/docs/beta (block units) + zero [18.75M, 25M)
// Phase E: K5 corner fill
__global__ __launch_bounds__(256, 2) void mega(Params p){
  cg::grid_group grid = cg::this_grid();
  __shared__ float smem[6800];   // 27.2 KB; 2 blocks/CU guaranteed
  int bid = blockIdx.x;          // 0..511
  int tid = threadIdx.x;         // 0..255

  // ---------------- Phase A ----------------
  {
    int w = tid>>6, lane = tid&63;
    float* ws0 = smem + w*512;   // per-wave scratch (512 floats)
    int F32 = sniffF32((const unsigned short*)p.X, lane);
#pragma unroll 1
    for (int rd=0; rd<2; rd++){
      int u = bid*4 + w + rd*2048;
      if (u >= NN+DD+1+DD+NN) continue;   // 2201 units
      if (u < NN){
        // CSR(A) row scan
        int i=u, nn=0;
        for (int base=0;base<NN;base+=64){
          int c=base+lane; float v=0.f;
          if (c<NN) v=ldf(p.A, i*NN+c, F32);
          unsigned long long m=__ballot(v!=0.f);
          if (v!=0.f){
            int pos=nn+__popcll(m&((1ull<<lane)-1ull));
            if (pos<ACAP){ p.a_idx[i*ACAP+pos]=c; p.a_val[i*ACAP+pos]=v; }
          }
          nn+=__popcll(m);
        }
        if (lane==0) p.a_nnz[i]=min(nn,ACAP);
      } else if (u < NN+DD){
        // mask word-list
        int d=u-NN, nn=0;
        for (int base=0;base<NN;base+=64){
          int c=base+lane; float v=0.f;
          if (c<NN) v=ldf(p.masks, d*NN+c, F32);
          unsigned long long m=__ballot(v!=0.f);
          if (v!=0.f){
            int pos=nn+__popcll(m&((1ull<<lane)-1ull));
            if (pos<MCAP) p.m_idx[d*MCAP+pos]=c;
          }
          nn+=__popcll(m);
        }
        if (lane==0) p.m_cnt[d]=min(nn,MCAP);
      } else if (u == NN+DD){
        // wpr (top-k straight-through mask) + init sumsq/flag
        for (int t=lane;t<FF;t+=64) ws0[t]=ldf(p.wm, t, F32);
        wave_lds_sync();
        float sp = 0.3f*(float)p.epoch[0]/(float)p.epochs[0];
        int j=(int)lroundf(sp*(float)FF);
        for (int t=lane;t<FF;t+=64){
          float v=ws0[t]; int r=0;
          for (int uu=0;uu<FF;uu++){ float vu=ws0[uu]; r += ((vu<v)||(vu==v && uu<t)) ? 1 : 0; }
          p.wpr[t] = (r>=j)? ldf(p.Wbeta, t, F32) : 0.f;
        }
        if (lane==0){ p.sumsq[0]=0.f; p.flag[0]=F32; }
      } else if (u < NN+DD+1+DD){
        // img MLP: limg[d] pre-sigmoid
        int d = u - (NN+DD+1);
        for (int t=lane;t<TIF;t+=64) ws0[t]=ldf(p.img, d*TIF+t, F32);
        wave_lds_sync();
        float acc=0.f;
        for (int h=lane; h<HDD; h+=64){
          float a=ldf(p.bm1, h, F32);
#pragma unroll 4
          for (int t=0;t<TIF;t++) a=fmaf(ws0[t], ldf(p.Wm1, t*HDD+h, F32), a);
          acc = fmaf(fmaxf(a,0.f), ldf(p.Wm2, h, F32), acc);
        }
#pragma unroll
        for (int o=32;o>0;o>>=1) acc += __shfl_down(acc,o,64);
        if (lane==0) p.limg[d]=acc+ldf(p.bm2,0,F32);
      } else {
        // XW row r = X[r] @ Wg1
        int r = u - (NN+DD+1+DD);
        for (int t=lane;t<FF;t+=64) ws0[t]=ldf(p.X, r*FF+t, F32);
        wave_lds_sync();
        for (int col=lane; col<FF; col+=64){
          float a=0.f;
#pragma unroll 4
          for (int c=0;c<FF;c++) a=fmaf(ws0[c], ldf(p.Wg1, c*FF+col, F32), a);
          p.XW[r*FF+col]=a;
        }
      }
    }
    zero_span(p.zb, 0L, 6250000L, bid, 512, tid, 256);
  }
  grid.sync();

  // ---------------- Phase B (K2 rows; 2 rows per block, half-block units) ----------------
  {
    int hb = tid>>7, tx = tid&127;
    float* sm = smem + hb*512;
    int*   sidx = (int*)sm;        // [0..95]
    float* sval = sm+96;           // [96..191]
    float* t1   = sm+192;          // [192..291]
    int row = bid*2+hb;
    bool act = (bid<500);
    int F32 = p.flag[0];
    int nn=0;
    if (act){
      nn=p.a_nnz[row];
      for (int t=tx;t<nn;t+=128){ sidx[t]=p.a_idx[row*ACAP+t]; sval[t]=p.a_val[row*ACAP+t]; }
    }
    __syncthreads();
    if (act && tx<FF){
      float a=0.f;
      for (int m=0;m<nn;m++) a=fmaf(sval[m], p.XW[sidx[m]*FF+tx], a);
      t1[tx]=fmaxf(a,0.f);
    }
    __syncthreads();
    if (act && tx<FF){
      float s=0.f;
#pragma unroll 4
      for (int c=0;c<FF;c++) s=fmaf(t1[c], ldf(p.Wg2, c*FF+tx, F32), s);
      p.H1W[row*FF+tx]=s;
    }
    zero_span(p.zb, 6250000L, 6250000L, bid, 512, tid, 256);
  }
  grid.sync();

  // ---------------- Phase C (K3 rows; 2 rows per block, half-block units) ----------------
  {
    int hb = tid>>7, tx = tid&127;
    float* sm = smem + hb*512;
    int*   sidx = (int*)sm;                       // [0..95]
    float* sval = sm+96;                          // [96..191]
    float* hr   = sm+192;                         // [192..291]
    float* t1   = sm+292;                         // [292..391]
    volatile float* red = (volatile float*)(sm+392); // [392..393]
    int i = bid*2+hb;
    bool act = (bid<500);
    int F32 = p.flag[0];
    int nn=0;
    if (act){
      nn=p.a_nnz[i];
      for (int t=tx;t<nn;t+=128){ sidx[t]=p.a_idx[i*ACAP+t]; sval[t]=p.a_val[i*ACAP+t]; }
    }
    __syncthreads();
    if (act && tx<FF){
      float a=0.f;
      for (int m=0;m<nn;m++) a=fmaf(sval[m], p.H1W[sidx[m]*FF+tx], a);
      hr[tx]=a; p.Hh[i*FF+tx]=a; p.out[(size_t)O_H+(size_t)i*FF+tx]=a;
    }
    __syncthreads();
    if (act && tx<FF){
      float a=ldf(p.bh1, tx, F32);
#pragma unroll 4
      for (int c=0;c<FF;c++) a=fmaf(hr[c], ldf(p.Wh1, c*FF+tx, F32), a);
      t1[tx]=fmaxf(a,0.f);
    }
    __syncthreads();
    float hel=0.f;
    if (act && tx<FF){
      float s=ldf(p.bh2, tx, F32);
#pragma unroll 4
      for (int c=0;c<FF;c++) s=fmaf(t1[c], ldf(p.Wh2, c*FF+tx, F32), s);
      hel=fmaxf(s,0.f);
    }
    float phw = (act && tx<FF)? hr[tx]*p.wpr[tx] : 0.f;
    float rs2 = blk_red_half(hel*hel, red, tx);
    float rhw = blk_red_half(phw, red, tx);
    if (act){
      float rinv = 1.f/fmaxf(sqrtf(rs2), 1e-12f);
      if (tx<FF){ float v=hel*rinv; p.Hn[i*FF+tx]=v; p.HnT[tx*NN+i]=v; }
      if (tx==0){ p.hw[i]=rhw; atomicAdd(p.sumsq, rhw*rhw); }
    }
    zero_span(p.zb, 12500000L, 6250000L, bid, 512, tid, 256);
  }
  grid.sync();

  // ---------------- Phase D (K4: Z_ tiles | docs | beta_) ----------------
  {
    int F32 = p.flag[0];
    if (bid < 256){
      // Z_ 64x64 tile, K chunked 2x50 (LDS 27.2 KB)
      int b=bid;
      int bi=(b&15)*64, bj=(b>>4)*64;
      float* At = smem;          // 50*68
      float* Bt = smem+3400;     // 50*68
      int tx=tid&15, ty=tid>>4;
      float acc[4][4]={};
#pragma unroll 1
      for (int kc=0;kc<2;kc++){
        __syncthreads();
        for (int t=tid;t<50*64;t+=256){
          int k=t>>6, ii=t&63;
          int gi=bi+ii, gj=bj+ii;
          At[k*68+ii] = (gi<NN)? p.HnT[(kc*50+k)*NN+gi] : 0.f;
          Bt[k*68+ii] = (gj<NN)? p.HnT[(kc*50+k)*NN+gj] : 0.f;
        }
        __syncthreads();
        for (int k=0;k<50;k++){
          float4 av=*(float4*)&At[k*68+4*ty];
          float4 bv=*(float4*)&Bt[k*68+4*tx];
          float aa[4]={av.x,av.y,av.z,av.w};
          float bb[4]={bv.x,bv.y,bv.z,bv.w};
#pragma unroll
          for (int q=0;q<4;q++)
#pragma unroll
            for (int r=0;r<4;r++) acc[q][r]=fmaf(aa[q],bb[r],acc[q][r]);
        }
      }
#pragma unroll
      for (int q=0;q<4;q++){
        int gi=bi+4*ty+q; if (gi>=NN) continue;
        float z[4];
#pragma unroll
        for (int r=0;r<4;r++) z[r]=fmaxf(acc[q][r],0.f);
        int gj0=bj+4*tx;
        if (gj0+3<NN){
          float4 zz; zz.x=z[0]; zz.y=z[1]; zz.z=z[2]; zz.w=z[3];
          *(float4*)&p.out[O_Z+(size_t)gi*NN+gj0]=zz;
        } else {
          for (int r=0;r<4;r++) if (gj0+r<NN) p.out[O_Z+(size_t)gi*NN+gj0+r]=z[r];
        }
        if (gi<EB && gj0<EB){
#pragma unroll
          for (int r=0;r<4;r++){
            int gj=gj0+r;
            float t2=2.f-2.f*z[r];
            p.Eblk[gi*EB+gj]=(gi==gj)?0.f:expf(-t2*t2);
          }
        }
      }
    } else if (bid < 356){
      // doc unit
      int d=bid-256;
      int* sidx=(int*)smem;                              // [0..191] ints
      volatile float* red=(volatile float*)(smem+192);   // [192..195]
      int cnt=p.m_cnt[d];
      for (int t=tid;t<cnt;t+=256) sidx[t]=p.m_idx[d*MCAP+t];
      __syncthreads();
      float accH=0.f, accS=0.f;
      if (tid<FF) for (int m=0;m<cnt;m++){ int n=sidx[m]; accH+=p.Hh[n*FF+tid]; accS+=p.Hn[n*FF+tid]; }
      float Hp = accH/fmaxf((float)cnt,1.f);
      float pmu = (tid<FF)? Hp*ldf(p.Wmu, tid, F32)  : 0.f;
      float peta= (tid<FF)? Hp*ldf(p.Weta, tid, F32) : 0.f;
      float pgam= (tid<FF)? Hp*ldf(p.Wgam, tid, F32) : 0.f;
      float phw=0.f;
      for (int m=tid;m<cnt;m+=256) phw+=p.hw[sidx[m]];
      float rmu =blk_red4(pmu,red,tid);
      float reta=blk_red4(peta,red,tid);
      float rgam=blk_red4(pgam,red,tid);
      float rs2 =blk_red4(accS*accS,red,tid);
      float rhw =blk_red4(phw,red,tid);
      if (tid==0){
        float mu =fmaxf(rmu +ldf(p.bmu,0,F32),   0.f);
        float eta=fmaxf(reta+ldf(p.beta_b,0,F32),0.f);
        float gam=fmaxf(rgam+ldf(p.bgam,0,F32),  0.f);
        float Zd =fmaxf(0.5f*(rs2-(float)cnt), 0.f);
        float beta=rhw/fmaxf(sqrtf(p.sumsq[0]),1e-12f);
        float lt=1.f/(1.f+expf(-(mu+beta+eta*expf(-gam*Zd))));
        p.out[O_LAM+d]=1.f/(1.f+expf(-(lt+p.limg[d])));
        p.out[O_GAM+d]=gam;
        p.out[O_ETA+d]=eta;
      }
    } else if (bid < 360){
      // beta_ finalize
      int i=(bid-356)*256+tid;
      if (i<NN){
        float rinv=1.f/fmaxf(sqrtf(p.sumsq[0]),1e-12f);
        p.out[O_B3+i]=p.hw[i]*rinv;
      }
    }
    zero_span(p.zb, 18750000L, 6250000L, bid, 512, tid, 256);
  }
  grid.sync();

  // ---------------- Phase E (K5 corner fill; all zeroing complete) ----------------
  if (bid < DD){
    int d=bid; int k=p.m_cnt[d]; if (k>EB) k=EB;
    int kk=k*k;
    for (int idx=tid; idx<kk; idx+=256){
      int i2=idx/k, j=idx-i2*k;
      float e=(i2==j)?0.f:p.Eblk[i2*EB+j];
      p.out[(size_t)O_ZE + (size_t)d*1000000 + (size_t)i2*1000 + j]=e;
    }
  }
}

extern "C" void kernel_launch(void* const* d_in, const int* in_sizes, int n_in,
                              void* d_out, int out_size, void* d_ws, size_t ws_size,
                              hipStream_t stream) {
  Params P;
  P.epoch  = (const int*)d_in[0];
  P.epochs = (const int*)d_in[1];
  P.A      = d_in[2];
  P.masks  = d_in[3];
  P.X      = d_in[4];
  P.img    = d_in[5];
  P.Wg1    = d_in[6];
  P.Wg2    = d_in[7];
  P.Wh1    = d_in[8];
  P.bh1    = d_in[9];
  P.Wh2    = d_in[10];
  P.bh2    = d_in[11];
  P.Wmu    = d_in[12];
  P.bmu    = d_in[13];
  P.Weta   = d_in[14];
  P.beta_b = d_in[15];
  P.Wgam   = d_in[16];
  P.bgam   = d_in[17];
  P.wm     = d_in[18];
  P.Wbeta  = d_in[19];
  P.Wm1    = d_in[20];
  P.bm1    = d_in[21];
  P.Wm2    = d_in[22];
  P.bm2    = d_in[23];
  P.out    = (float*)d_out;

  float* ws   = (float*)d_ws;
  P.XW   = ws;                    // 100000
  P.H1W  = P.XW  + 100000;
  P.Hh   = P.H1W + 100000;
  P.Hn   = P.Hh  + 100000;
  P.HnT  = P.Hn  + 100000;
  P.Eblk = P.HnT + 100000;        // 65536
  P.a_val= P.Eblk+ 65536;         // 96000
  P.a_idx= (int*)(P.a_val + 96000); // 96000
  P.a_nnz= P.a_idx + 96000;       // 1000
  P.m_idx= P.a_nnz + 1000;        // 19200
  P.m_cnt= P.m_idx + 19200;       // 100
  P.wpr  = (float*)(P.m_cnt + 100); // 100
  P.hw   = P.wpr + 100;           // 1000
  P.sumsq= P.hw + 1000;           // 4
  P.flag = (int*)(P.sumsq + 4);   // 4
  P.limg = (float*)(P.flag + 4);  // 128

  P.zb = (uint4*)((char*)d_out + (size_t)O_ZE*4); // 16B-aligned, 25M uint4s

  void* kargs[] = { (void*)&P };
  hipLaunchCooperativeKernel((const void*)mega, dim3(512), dim3(256), kargs, 0, stream);
}

// Round 4
// 666.347 us; speedup vs baseline: 1.4046x; 1.4046x over previous
//
#include <hip/hip_runtime.h>
#include <hip/hip_bf16.h>

typedef __hip_bfloat16 bf;
typedef unsigned int u32x4 __attribute__((ext_vector_type(4)));

#define NN   1000
#define DD   100
#define FF   100
#define TIF  512
#define HDD  128
#define EB   256
#define ACAP 96
#define MCAP 192

// output layout (element offsets, float32)
#define O_LAM 0
#define O_Z   100
#define O_B3  1000100
#define O_GAM 1001100
#define O_ETA 1001200
#define O_ZE  1001300
#define O_H   101001300

// dtype-agnostic input load: F32=1 -> buffer is float32, else bf16
__device__ __forceinline__ float ldf(const void* p, int i, int F32){
  return F32 ? ((const float*)p)[i] : __bfloat162float(((const __hip_bfloat16*)p)[i]);
}

// 2-wave (128-thread) block reduction
__device__ __forceinline__ float blk_red(float v, volatile float* red, int tid){
#pragma unroll
  for (int o=32;o>0;o>>=1) v += __shfl_down(v,o,64);
  if ((tid&63)==0) red[tid>>6]=v;
  __syncthreads();
  float r = red[0]+red[1];
  __syncthreads();
  return r;
}
// 4-wave (256-thread) block reduction
__device__ __forceinline__ float blk_red4(float v, volatile float* red, int tid){
#pragma unroll
  for (int o=32;o>0;o>>=1) v += __shfl_down(v,o,64);
  if ((tid&63)==0) red[tid>>6]=v;
  __syncthreads();
  float r = red[0]+red[1]+red[2]+red[3];
  __syncthreads();
  return r;
}

// per-wave dtype sniff over first 512 u16 of X: f32 buffer -> ~12.5% exps >= 0xE0
__device__ __forceinline__ int sniffF32(const unsigned short* __restrict__ p, int tid){
  int lane = tid & 63;
  const ushort4* q = (const ushort4*)p;
  ushort4 a = q[lane*2], b = q[lane*2+1];
  int c = 0;
  c += (((a.x>>7)&0xFF)>=0xE0); c += (((a.y>>7)&0xFF)>=0xE0);
  c += (((a.z>>7)&0xFF)>=0xE0); c += (((a.w>>7)&0xFF)>=0xE0);
  c += (((b.x>>7)&0xFF)>=0xE0); c += (((b.y>>7)&0xFF)>=0xE0);
  c += (((b.z>>7)&0xFF)>=0xE0); c += (((b.w>>7)&0xFF)>=0xE0);
#pragma unroll
  for (int o=32;o>0;o>>=1) c += __shfl_xor(c,o,64);
  return c > 8;
}

// zeroing block zi of nzb handles its chunk of [off, off+cnt) 16B quads
// nontemporal (skip L2 allocate); 4x unrolled for store MLP
__device__ __forceinline__ void zero_span(uint4* __restrict__ zb_, long off, long cnt,
                                          int zi, int nzb, int tid, int bdim){
  u32x4* __restrict__ zb = (u32x4*)zb_;
  long per = (cnt + nzb - 1)/nzb;
  long s = (long)zi*per; if (s>cnt) s=cnt;
  long e = s+per; if (e>cnt) e=cnt;
  u32x4 z = (u32x4)(0u,0u,0u,0u);
  long i = off+s+tid, end = off+e, step = (long)bdim;
  for (; i+3*step < end; i += 4*step){
    __builtin_nontemporal_store(z, &zb[i]);
    __builtin_nontemporal_store(z, &zb[i+step]);
    __builtin_nontemporal_store(z, &zb[i+2*step]);
    __builtin_nontemporal_store(z, &zb[i+3*step]);
  }
  for (; i < end; i += step) __builtin_nontemporal_store(z, &zb[i]);
}

// ============ K1: build CSR(A), word-lists, wpr, img-MLP, flag, XW; zero [0,10M) ============
// work blocks (2201) and zero blocks (2500) interleaved by blockIdx parity
__global__ void k1_build(const void* __restrict__ A, const void* __restrict__ masks,
                         const void* __restrict__ wm, const void* __restrict__ Wbeta,
                         const void* __restrict__ img, const void* __restrict__ Wm1,
                         const void* __restrict__ bm1, const void* __restrict__ Wm2,
                         const void* __restrict__ bm2, const void* __restrict__ X,
                         const void* __restrict__ Wg1,
                         const int* epoch, const int* epochs,
                         int* a_idx, float* a_val, int* a_nnz,
                         int* m_idx, int* m_cnt, float* wpr, float* sumsq,
                         float* limg, int* flag, float* __restrict__ XW,
                         uint4* __restrict__ zb){
  int bid = blockIdx.x; int lane = threadIdx.x;
  int wi = -1, zi = -1;
  if (bid < 4402){ if (bid & 1) zi = bid >> 1; else wi = bid >> 1; }
  else zi = 2201 + (bid - 4402);
  if (wi >= 2201) { wi = -1; zi = -2; }   // (unused guard)
  if (zi >= 0){ zero_span(zb, 0L, 10000000L, zi, 2500, lane, 64); return; }
  if (zi == -2) return;
  int b = wi;  // 0..2200
  int F32 = sniffF32((const unsigned short*)X, lane);
  if (b < NN){
    int i=b, nn=0;
    for (int base=0;base<NN;base+=64){
      int c=base+lane; float v=0.f;
      if (c<NN) v=ldf(A, i*NN+c, F32);
      unsigned long long m=__ballot(v!=0.f);
      if (v!=0.f){
        int pos=nn+__popcll(m&((1ull<<lane)-1ull));
        if (pos<ACAP){ a_idx[i*ACAP+pos]=c; a_val[i*ACAP+pos]=v; }
      }
      nn+=__popcll(m);
    }
    if (lane==0) a_nnz[i]=min(nn,ACAP);
  } else if (b < NN+DD){
    int d=b-NN, nn=0;
    for (int base=0;base<NN;base+=64){
      int c=base+lane; float v=0.f;
      if (c<NN) v=ldf(masks, d*NN+c, F32);
      unsigned long long m=__ballot(v!=0.f);
      if (v!=0.f){
        int pos=nn+__popcll(m&((1ull<<lane)-1ull));
        if (pos<MCAP) m_idx[d*MCAP+pos]=c;
      }
      nn+=__popcll(m);
    }
    if (lane==0) m_cnt[d]=min(nn,MCAP);
  } else if (b == NN+DD){
    __shared__ float w[FF];
    for (int t=lane;t<FF;t+=64) w[t]=ldf(wm, t, F32);
    __syncthreads();
    float sp = 0.3f*(float)epoch[0]/(float)epochs[0];
    int j=(int)lroundf(sp*(float)FF);
    for (int t=lane;t<FF;t+=64){
      float v=w[t]; int r=0;
      for (int u=0;u<FF;u++){ float vu=w[u]; r += ((vu<v)||(vu==v && u<t)) ? 1 : 0; }
      wpr[t] = (r>=j)? ldf(Wbeta, t, F32) : 0.f;
    }
    if (lane==0){ sumsq[0]=0.f; flag[0]=F32; }
  } else if (b < NN+DD+1+DD){
    // img MLP: limg[d] = MLP(img[d]) pre-sigmoid
    int d = b - (NN+DD+1);
    __shared__ float ir[TIF];
    for (int t=lane;t<TIF;t+=64) ir[t]=ldf(img, d*TIF+t, F32);
    __syncthreads();
    float acc=0.f;
    for (int h=lane; h<HDD; h+=64){
      float a=ldf(bm1, h, F32);
#pragma unroll 4
      for (int t=0;t<TIF;t++) a=fmaf(ir[t], ldf(Wm1, t*HDD+h, F32), a);
      acc = fmaf(fmaxf(a,0.f), ldf(Wm2, h, F32), acc);
    }
#pragma unroll
    for (int o=32;o>0;o>>=1) acc += __shfl_down(acc,o,64);
    if (lane==0) limg[d]=acc+ldf(bm2,0,F32);
  } else {
    // XW row r = X[r] @ Wg1
    int r = b - (NN+DD+1+DD);
    __shared__ float ar[FF];
    for (int t=lane;t<FF;t+=64) ar[t]=ldf(X, r*FF+t, F32);
    __syncthreads();
    for (int col=lane; col<FF; col+=64){
      float a=0.f;
#pragma unroll 4
      for (int c=0;c<FF;c++) a=fmaf(ar[c], ldf(Wg1, c*FF+col, F32), a);
      XW[r*FF+col]=a;
    }
  }
}

// ============ K2: per-row H1=relu(A@XW), H1W=H1@Wg2; zero [10M,17.5M) ============
__global__ void k2_h1(const float* __restrict__ XW, const void* __restrict__ Wg2,
                      const int* flag, const int* __restrict__ a_idx,
                      const float* __restrict__ a_val, const int* __restrict__ a_nnz,
                      float* __restrict__ H1W, uint4* __restrict__ zb){
  int bid=blockIdx.x, tx=threadIdx.x;
  int wi=-1, zi=-1;
  if (bid < 2000){ if (bid & 1) zi = bid >> 1; else wi = bid >> 1; }
  else zi = 1000 + (bid - 2000);
  if (zi >= 0){ zero_span(zb, 10000000L, 7500000L, zi, 1875, tx, 128); return; }
  int row = wi;
  __shared__ int sidx[ACAP]; __shared__ float sval[ACAP]; __shared__ float t1[FF];
  int nn=a_nnz[row];
  for (int t=tx;t<nn;t+=128){ sidx[t]=a_idx[row*ACAP+t]; sval[t]=a_val[row*ACAP+t]; }
  __syncthreads();
  if (tx<FF){
    float a=0.f;
    for (int m=0;m<nn;m++) a=fmaf(sval[m], XW[sidx[m]*FF+tx], a);
    t1[tx]=fmaxf(a,0.f);
  }
  __syncthreads();
  int F32=flag[0];
  if (tx<FF){
    float s=0.f;
#pragma unroll 4
    for (int c=0;c<FF;c++) s=fmaf(t1[c], ldf(Wg2, c*FF+tx, F32), s);
    H1W[row*FF+tx]=s;
  }
}

// ============ K3: per-row H=A@H1W (+H out), rowchain: Hn/HnT/hw/sumsq; zero [17.5M,25M) ============
__global__ void k3_h2(const float* __restrict__ H1W, const int* __restrict__ a_idx,
                      const float* __restrict__ a_val, const int* __restrict__ a_nnz,
                      const void* __restrict__ Wh1, const void* __restrict__ bh1,
                      const void* __restrict__ Wh2, const void* __restrict__ bh2,
                      const float* __restrict__ wpr, const int* flag,
                      float* __restrict__ Hh, float* __restrict__ Hn,
                      float* __restrict__ HnT, float* __restrict__ hw, float* sumsq,
                      float* __restrict__ outH, uint4* __restrict__ zb){
  int bid=blockIdx.x, tx=threadIdx.x;
  int wi=-1, zi=-1;
  if (bid < 2000){ if (bid & 1) zi = bid >> 1; else wi = bid >> 1; }
  else zi = 1000 + (bid - 2000);
  if (zi >= 0){ zero_span(zb, 17500000L, 7500000L, zi, 1875, tx, 128); return; }
  int i = wi;
  __shared__ int sidx[ACAP]; __shared__ float sval[ACAP];
  __shared__ float hr[FF], t1[FF];
  __shared__ float red[2];
  int nn=a_nnz[i];
  for (int t=tx;t<nn;t+=128){ sidx[t]=a_idx[i*ACAP+t]; sval[t]=a_val[i*ACAP+t]; }
  __syncthreads();
  if (tx<FF){
    float a=0.f;
    for (int m=0;m<nn;m++) a=fmaf(sval[m], H1W[sidx[m]*FF+tx], a);
    hr[tx]=a; Hh[i*FF+tx]=a; outH[i*FF+tx]=a;
  }
  __syncthreads();
  int F32=flag[0];
  if (tx<FF){
    float a=ldf(bh1, tx, F32);
#pragma unroll 4
    for (int c=0;c<FF;c++) a=fmaf(hr[c], ldf(Wh1, c*FF+tx, F32), a);
    t1[tx]=fmaxf(a,0.f);
  }
  __syncthreads();
  float hel=0.f;
  if (tx<FF){
    float s=ldf(bh2, tx, F32);
#pragma unroll 4
    for (int c=0;c<FF;c++) s=fmaf(t1[c], ldf(Wh2, c*FF+tx, F32), s);
    hel=fmaxf(s,0.f);
  }
  float phw = (tx<FF)? hr[tx]*wpr[tx] : 0.f;
  float rs2 = blk_red(hel*hel, red, tx);
  float rhw = blk_red(phw, red, tx);
  float rinv = 1.f/fmaxf(sqrtf(rs2), 1e-12f);
  if (tx<FF){ float v=hel*rinv; Hn[i*FF+tx]=v; HnT[tx*NN+i]=v; }
  if (tx==0){ hw[i]=rhw; atomicAdd(sumsq, rhw*rhw); }
}

// ============ K4: Z_ tiles + E block | docs | beta_ (no zeroing) ============
__global__ __launch_bounds__(256) void k4_zdoc(const float* __restrict__ HnT,
                      const float* __restrict__ Hh, const float* __restrict__ Hn,
                      const float* __restrict__ hw, const float* __restrict__ sumsq,
                      const int* __restrict__ m_idx, const int* __restrict__ m_cnt,
                      const void* Wmu, const void* bmu, const void* Weta, const void* beta_b,
                      const void* Wgam, const void* bgam, const int* flag,
                      const float* __restrict__ limg,
                      float* __restrict__ out, float* __restrict__ Eblk){
  int b=blockIdx.x, tid=threadIdx.x;
  if (b < 256){
    // ---- Z_ tile ----
    int bi=(b&15)*64, bj=(b>>4)*64;
    __shared__ float At[FF*68], Bt[FF*68];
    for (int t=tid;t<FF*64;t+=256){
      int k=t>>6, ii=t&63;
      int gi=bi+ii, gj=bj+ii;
      At[k*68+ii] = (gi<NN)? HnT[k*NN+gi] : 0.f;
      Bt[k*68+ii] = (gj<NN)? HnT[k*NN+gj] : 0.f;
    }
    __syncthreads();
    int tx=tid&15, ty=tid>>4;
    float acc[4][4]={};
    for (int k=0;k<FF;k++){
      float4 av=*(float4*)&At[k*68+4*ty];
      float4 bv=*(float4*)&Bt[k*68+4*tx];
      float aa[4]={av.x,av.y,av.z,av.w};
      float bb[4]={bv.x,bv.y,bv.z,bv.w};
#pragma unroll
      for (int q=0;q<4;q++)
#pragma unroll
        for (int r=0;r<4;r++) acc[q][r]=fmaf(aa[q],bb[r],acc[q][r]);
    }
#pragma unroll
    for (int q=0;q<4;q++){
      int gi=bi+4*ty+q; if (gi>=NN) continue;
      float z[4];
#pragma unroll
      for (int r=0;r<4;r++) z[r]=fmaxf(acc[q][r],0.f);
      int gj0=bj+4*tx;
      if (gj0+3<NN){
        float4 zz; zz.x=z[0]; zz.y=z[1]; zz.z=z[2]; zz.w=z[3];
        *(float4*)&out[O_Z+(size_t)gi*NN+gj0]=zz;
      } else {
        for (int r=0;r<4;r++) if (gj0+r<NN) out[O_Z+(size_t)gi*NN+gj0+r]=z[r];
      }
      if (gi<EB && gj0<EB){
#pragma unroll
        for (int r=0;r<4;r++){
          int gj=gj0+r;
          float t2=2.f-2.f*z[r];
          Eblk[gi*EB+gj]=(gi==gj)?0.f:expf(-t2*t2);
        }
      }
    }
    return;
  }
  if (b >= 356){
    int i=(b-356)*256+tid;
    if (i<NN){
      float rinv=1.f/fmaxf(sqrtf(sumsq[0]),1e-12f);
      out[O_B3+i]=hw[i]*rinv;
    }
    return;
  }
  // ---- doc ----
  int d=b-256;
  int F32 = flag[0];
  __shared__ int sidx[MCAP]; __shared__ float red[4];
  int cnt=m_cnt[d];
  for (int t=tid;t<cnt;t+=256) sidx[t]=m_idx[d*MCAP+t];
  __syncthreads();
  float accH=0.f, accS=0.f;
  if (tid<FF) for (int m=0;m<cnt;m++){ int n=sidx[m]; accH+=Hh[n*FF+tid]; accS+=Hn[n*FF+tid]; }
  float Hp = accH/fmaxf((float)cnt,1.f);
  float pmu = (tid<FF)? Hp*ldf(Wmu, tid, F32)  : 0.f;
  float peta= (tid<FF)? Hp*ldf(Weta, tid, F32) : 0.f;
  float pgam= (tid<FF)? Hp*ldf(Wgam, tid, F32) : 0.f;
  float phw=0.f;
  for (int m=tid;m<cnt;m+=256) phw+=hw[sidx[m]];
  float rmu =blk_red4(pmu,red,tid);
  float reta=blk_red4(peta,red,tid);
  float rgam=blk_red4(pgam,red,tid);
  float rs2 =blk_red4(accS*accS,red,tid);
  float rhw =blk_red4(phw,red,tid);
  if (tid==0){
    float mu =fmaxf(rmu +ldf(bmu,0,F32),   0.f);
    float eta=fmaxf(reta+ldf(beta_b,0,F32),0.f);
    float gam=fmaxf(rgam+ldf(bgam,0,F32),  0.f);
    float Zd =fmaxf(0.5f*(rs2-(float)cnt), 0.f);
    float beta=rhw/fmaxf(sqrtf(sumsq[0]),1e-12f);
    float lt=1.f/(1.f+expf(-(mu+beta+eta*expf(-gam*Zd))));
    out[O_LAM+d]=1.f/(1.f+expf(-(lt+limg[d])));
    out[O_GAM+d]=gam;
    out[O_ETA+d]=eta;
  }
}

// ============ K5: fill nonzero k x k blocks of Z_event ============
__global__ void k5_fill(const float* __restrict__ Eblk, const int* __restrict__ m_cnt,
                        float* __restrict__ outZE){
  int d=blockIdx.x; int k=m_cnt[d]; if (k>EB) k=EB;
  int kk=k*k;
  for (int idx=threadIdx.x; idx<kk; idx+=256){
    int i=idx/k, j=idx-i*k;
    float e=(i==j)?0.f:Eblk[i*EB+j];
    outZE[(size_t)d*1000000 + (size_t)i*1000 + j]=e;
  }
}

extern "C" void kernel_launch(void* const* d_in, const int* in_sizes, int n_in,
                              void* d_out, int out_size, void* d_ws, size_t ws_size,
                              hipStream_t stream) {
  const int* epoch  = (const int*)d_in[0];
  const int* epochs = (const int*)d_in[1];
  const void* A     = d_in[2];
  const void* masks = d_in[3];
  const void* X     = d_in[4];
  const void* img   = d_in[5];
  const void* Wg1   = d_in[6];
  const void* Wg2   = d_in[7];
  const void* Wh1   = d_in[8];
  const void* bh1   = d_in[9];
  const void* Wh2   = d_in[10];
  const void* bh2   = d_in[11];
  const void* Wmu   = d_in[12];
  const void* bmu   = d_in[13];
  const void* Weta  = d_in[14];
  const void* beta_b= d_in[15];
  const void* Wgam  = d_in[16];
  const void* bgam  = d_in[17];
  const void* wm    = d_in[18];
  const void* Wbeta = d_in[19];
  const void* Wm1   = d_in[20];
  const void* bm1   = d_in[21];
  const void* Wm2   = d_in[22];
  const void* bm2   = d_in[23];
  float* out = (float*)d_out;

  float* ws   = (float*)d_ws;
  float* XW   = ws;               // 100000
  float* H1W  = XW  + 100000;
  float* Hh   = H1W + 100000;
  float* Hn   = Hh  + 100000;
  float* HnT  = Hn  + 100000;
  float* Eblk = HnT + 100000;     // 65536
  float* a_val= Eblk+ 65536;      // 96000
  int* a_idx  = (int*)(a_val + 96000); // 96000
  int* a_nnz  = a_idx + 96000;    // 1000
  int* m_idx  = a_nnz + 1000;     // 19200
  int* m_cnt  = m_idx + 19200;    // 100
  float* wpr  = (float*)(m_cnt + 100); // 100
  float* hw   = wpr + 100;        // 1000
  float* sumsq= hw + 1000;        // 4
  int* flag   = (int*)(sumsq + 4); // 4
  float* limg = (float*)(flag + 4); // 128

  uint4* zb = (uint4*)((char*)d_out + (size_t)O_ZE*4); // 16B-aligned, 25M uint4s

  // K1: build + img MLP + XW; zero [0, 10M) interleaved (2201 work + 2500 zero)
  hipLaunchKernelGGL(k1_build, dim3(4402+299), dim3(64), 0, stream,
                     A, masks, wm, Wbeta, img, Wm1, bm1, Wm2, bm2, X, Wg1,
                     epoch, epochs,
                     a_idx, a_val, a_nnz, m_idx, m_cnt, wpr, sumsq, limg, flag, XW, zb);
  // K2: H1 + H1W; zero [10M, 17.5M) interleaved (1000 work + 1875 zero)
  hipLaunchKernelGGL(k2_h1, dim3(2875), dim3(128), 0, stream,
                     XW, Wg2, flag, a_idx, a_val, a_nnz, H1W, zb);
  // K3: H + rowchain; zero [17.5M, 25M) interleaved (1000 work + 1875 zero)
  hipLaunchKernelGGL(k3_h2, dim3(2875), dim3(128), 0, stream,
                     H1W, a_idx, a_val, a_nnz, Wh1, bh1, Wh2, bh2, wpr, flag,
                     Hh, Hn, HnT, hw, sumsq, out + O_H, zb);
  // K4: Z_ + E | docs | beta_ (no zeroing)
  hipLaunchKernelGGL(k4_zdoc, dim3(360), dim3(256), 0, stream,
                     HnT, Hh, Hn, hw, sumsq, m_idx, m_cnt,
                     Wmu, bmu, Weta, beta_b, Wgam, bgam, flag, limg,
                     out, Eblk);
  // K5: fill nonzero Z_event blocks (zeroing completed in K1-K3)
  hipLaunchKernelGGL(k5_fill, dim3(DD), dim3(256), 0, stream, Eblk, m_cnt, out + O_ZE);
}

// Round 5
// 660.011 us; speedup vs baseline: 1.4181x; 1.0096x over previous
//
#include <hip/hip_runtime.h>
#include <hip/hip_bf16.h>

typedef __hip_bfloat16 bf;

#define NN   1000
#define DD   100
#define FF   100
#define TIF  512
#define HDD  128
#define EB   256
#define ACAP 96
#define MCAP 192

// output layout (element offsets, float32)
#define O_LAM 0
#define O_Z   100
#define O_B3  1000100
#define O_GAM 1001100
#define O_ETA 1001200
#define O_ZE  1001300
#define O_H   101001300

// dtype-agnostic input load: F32=1 -> buffer is float32, else bf16
__device__ __forceinline__ float ldf(const void* p, int i, int F32){
  return F32 ? ((const float*)p)[i] : __bfloat162float(((const __hip_bfloat16*)p)[i]);
}

// 2-wave (128-thread) block reduction
__device__ __forceinline__ float blk_red(float v, volatile float* red, int tid){
#pragma unroll
  for (int o=32;o>0;o>>=1) v += __shfl_down(v,o,64);
  if ((tid&63)==0) red[tid>>6]=v;
  __syncthreads();
  float r = red[0]+red[1];
  __syncthreads();
  return r;
}
// 4-wave (256-thread) block reduction
__device__ __forceinline__ float blk_red4(float v, volatile float* red, int tid){
#pragma unroll
  for (int o=32;o>0;o>>=1) v += __shfl_down(v,o,64);
  if ((tid&63)==0) red[tid>>6]=v;
  __syncthreads();
  float r = red[0]+red[1]+red[2]+red[3];
  __syncthreads();
  return r;
}

// per-wave dtype sniff over first 512 u16 of X: f32 buffer -> ~12.5% exps >= 0xE0
__device__ __forceinline__ int sniffF32(const unsigned short* __restrict__ p, int tid){
  int lane = tid & 63;
  const ushort4* q = (const ushort4*)p;
  ushort4 a = q[lane*2], b = q[lane*2+1];
  int c = 0;
  c += (((a.x>>7)&0xFF)>=0xE0); c += (((a.y>>7)&0xFF)>=0xE0);
  c += (((a.z>>7)&0xFF)>=0xE0); c += (((a.w>>7)&0xFF)>=0xE0);
  c += (((b.x>>7)&0xFF)>=0xE0); c += (((b.y>>7)&0xFF)>=0xE0);
  c += (((b.z>>7)&0xFF)>=0xE0); c += (((b.w>>7)&0xFF)>=0xE0);
#pragma unroll
  for (int o=32;o>0;o>>=1) c += __shfl_xor(c,o,64);
  return c > 8;
}

// zeroing block zi of nzb handles its chunk of [off, off+cnt) uint4s
// PLAIN stores (same path as the harness fill, which sustains 6.3 TB/s);
// nt-flagged stores measured ~4 TB/s aggregate in R2/R4 — reverted.
__device__ __forceinline__ void zero_span(uint4* __restrict__ zb, long off, long cnt,
                                          int zi, int nzb, int tid, int bdim){
  long per = (cnt + nzb - 1)/nzb;
  long s = (long)zi*per; if (s>cnt) s=cnt;
  long e = s+per; if (e>cnt) e=cnt;
  uint4 z; z.x=z.y=z.z=z.w=0u;
  for (long i=off+s+tid; i<off+e; i+=bdim) zb[i]=z;
}

// ============ K1: build CSR(A), word-lists, wpr, img-MLP, flag, XW; zero [0,8M) ============
// work blocks (2201) and zero blocks (2048) interleaved by blockIdx parity so the
// BW-bound zeroing overlaps the latency-bound compute instead of trailing it.
__global__ void k1_build(const void* __restrict__ A, const void* __restrict__ masks,
                         const void* __restrict__ wm, const void* __restrict__ Wbeta,
                         const void* __restrict__ img, const void* __restrict__ Wm1,
                         const void* __restrict__ bm1, const void* __restrict__ Wm2,
                         const void* __restrict__ bm2, const void* __restrict__ X,
                         const void* __restrict__ Wg1,
                         const int* epoch, const int* epochs,
                         int* a_idx, float* a_val, int* a_nnz,
                         int* m_idx, int* m_cnt, float* wpr, float* sumsq,
                         float* limg, int* flag, float* __restrict__ XW,
                         uint4* __restrict__ zb){
  int bid = blockIdx.x; int lane = threadIdx.x;
  int wi = -1, zi = -1;
  if (bid < 4096){ if (bid & 1) zi = bid >> 1; else wi = bid >> 1; }
  else wi = 2048 + (bid - 4096);
  if (zi >= 0){ zero_span(zb, 0L, 8000000L, zi, 2048, lane, 64); return; }
  int b = wi;  // 0..2200
  int F32 = sniffF32((const unsigned short*)X, lane);
  if (b < NN){
    int i=b, nn=0;
    for (int base=0;base<NN;base+=64){
      int c=base+lane; float v=0.f;
      if (c<NN) v=ldf(A, i*NN+c, F32);
      unsigned long long m=__ballot(v!=0.f);
      if (v!=0.f){
        int pos=nn+__popcll(m&((1ull<<lane)-1ull));
        if (pos<ACAP){ a_idx[i*ACAP+pos]=c; a_val[i*ACAP+pos]=v; }
      }
      nn+=__popcll(m);
    }
    if (lane==0) a_nnz[i]=min(nn,ACAP);
  } else if (b < NN+DD){
    int d=b-NN, nn=0;
    for (int base=0;base<NN;base+=64){
      int c=base+lane; float v=0.f;
      if (c<NN) v=ldf(masks, d*NN+c, F32);
      unsigned long long m=__ballot(v!=0.f);
      if (v!=0.f){
        int pos=nn+__popcll(m&((1ull<<lane)-1ull));
        if (pos<MCAP) m_idx[d*MCAP+pos]=c;
      }
      nn+=__popcll(m);
    }
    if (lane==0) m_cnt[d]=min(nn,MCAP);
  } else if (b == NN+DD){
    __shared__ float w[FF];
    for (int t=lane;t<FF;t+=64) w[t]=ldf(wm, t, F32);
    __syncthreads();
    float sp = 0.3f*(float)epoch[0]/(float)epochs[0];
    int j=(int)lroundf(sp*(float)FF);
    for (int t=lane;t<FF;t+=64){
      float v=w[t]; int r=0;
      for (int u=0;u<FF;u++){ float vu=w[u]; r += ((vu<v)||(vu==v && u<t)) ? 1 : 0; }
      wpr[t] = (r>=j)? ldf(Wbeta, t, F32) : 0.f;
    }
    if (lane==0){ sumsq[0]=0.f; flag[0]=F32; }
  } else if (b < NN+DD+1+DD){
    // img MLP: limg[d] = MLP(img[d]) pre-sigmoid
    int d = b - (NN+DD+1);
    __shared__ float ir[TIF];
    for (int t=lane;t<TIF;t+=64) ir[t]=ldf(img, d*TIF+t, F32);
    __syncthreads();
    float acc=0.f;
    for (int h=lane; h<HDD; h+=64){
      float a=ldf(bm1, h, F32);
#pragma unroll 4
      for (int t=0;t<TIF;t++) a=fmaf(ir[t], ldf(Wm1, t*HDD+h, F32), a);
      acc = fmaf(fmaxf(a,0.f), ldf(Wm2, h, F32), acc);
    }
#pragma unroll
    for (int o=32;o>0;o>>=1) acc += __shfl_down(acc,o,64);
    if (lane==0) limg[d]=acc+ldf(bm2,0,F32);
  } else {
    // XW row r = X[r] @ Wg1
    int r = b - (NN+DD+1+DD);
    __shared__ float ar[FF];
    for (int t=lane;t<FF;t+=64) ar[t]=ldf(X, r*FF+t, F32);
    __syncthreads();
    for (int col=lane; col<FF; col+=64){
      float a=0.f;
#pragma unroll 4
      for (int c=0;c<FF;c++) a=fmaf(ar[c], ldf(Wg1, c*FF+col, F32), a);
      XW[r*FF+col]=a;
    }
  }
}

// ============ K2: per-row H1=relu(A@XW), H1W=H1@Wg2; zero [8M,13M) ============
__global__ void k2_h1(const float* __restrict__ XW, const void* __restrict__ Wg2,
                      const int* flag, const int* __restrict__ a_idx,
                      const float* __restrict__ a_val, const int* __restrict__ a_nnz,
                      float* __restrict__ H1W, uint4* __restrict__ zb){
  int bid=blockIdx.x, tx=threadIdx.x;
  int wi=-1, zi=-1;
  if (bid < 2000){ if (bid & 1) zi = bid >> 1; else wi = bid >> 1; }
  else zi = 1000 + (bid - 2000);
  if (zi >= 0){ zero_span(zb, 8000000L, 5000000L, zi, 1280, tx, 128); return; }
  int row = wi;
  __shared__ int sidx[ACAP]; __shared__ float sval[ACAP]; __shared__ float t1[FF];
  int nn=a_nnz[row];
  for (int t=tx;t<nn;t+=128){ sidx[t]=a_idx[row*ACAP+t]; sval[t]=a_val[row*ACAP+t]; }
  __syncthreads();
  if (tx<FF){
    float a=0.f;
    for (int m=0;m<nn;m++) a=fmaf(sval[m], XW[sidx[m]*FF+tx], a);
    t1[tx]=fmaxf(a,0.f);
  }
  __syncthreads();
  int F32=flag[0];
  if (tx<FF){
    float s=0.f;
#pragma unroll 4
    for (int c=0;c<FF;c++) s=fmaf(t1[c], ldf(Wg2, c*FF+tx, F32), s);
    H1W[row*FF+tx]=s;
  }
}

// ============ K3: per-row H=A@H1W (+H out), rowchain: Hn/HnT/hw/sumsq; zero [13M,18M) ============
__global__ void k3_h2(const float* __restrict__ H1W, const int* __restrict__ a_idx,
                      const float* __restrict__ a_val, const int* __restrict__ a_nnz,
                      const void* __restrict__ Wh1, const void* __restrict__ bh1,
                      const void* __restrict__ Wh2, const void* __restrict__ bh2,
                      const float* __restrict__ wpr, const int* flag,
                      float* __restrict__ Hh, float* __restrict__ Hn,
                      float* __restrict__ HnT, float* __restrict__ hw, float* sumsq,
                      float* __restrict__ outH, uint4* __restrict__ zb){
  int bid=blockIdx.x, tx=threadIdx.x;
  int wi=-1, zi=-1;
  if (bid < 2000){ if (bid & 1) zi = bid >> 1; else wi = bid >> 1; }
  else zi = 1000 + (bid - 2000);
  if (zi >= 0){ zero_span(zb, 13000000L, 5000000L, zi, 1280, tx, 128); return; }
  int i = wi;
  __shared__ int sidx[ACAP]; __shared__ float sval[ACAP];
  __shared__ float hr[FF], t1[FF];
  __shared__ float red[2];
  int nn=a_nnz[i];
  for (int t=tx;t<nn;t+=128){ sidx[t]=a_idx[i*ACAP+t]; sval[t]=a_val[i*ACAP+t]; }
  __syncthreads();
  if (tx<FF){
    float a=0.f;
    for (int m=0;m<nn;m++) a=fmaf(sval[m], H1W[sidx[m]*FF+tx], a);
    hr[tx]=a; Hh[i*FF+tx]=a; outH[i*FF+tx]=a;
  }
  __syncthreads();
  int F32=flag[0];
  if (tx<FF){
    float a=ldf(bh1, tx, F32);
#pragma unroll 4
    for (int c=0;c<FF;c++) a=fmaf(hr[c], ldf(Wh1, c*FF+tx, F32), a);
    t1[tx]=fmaxf(a,0.f);
  }
  __syncthreads();
  float hel=0.f;
  if (tx<FF){
    float s=ldf(bh2, tx, F32);
#pragma unroll 4
    for (int c=0;c<FF;c++) s=fmaf(t1[c], ldf(Wh2, c*FF+tx, F32), s);
    hel=fmaxf(s,0.f);
  }
  float phw = (tx<FF)? hr[tx]*wpr[tx] : 0.f;
  float rs2 = blk_red(hel*hel, red, tx);
  float rhw = blk_red(phw, red, tx);
  float rinv = 1.f/fmaxf(sqrtf(rs2), 1e-12f);
  if (tx<FF){ float v=hel*rinv; Hn[i*FF+tx]=v; HnT[tx*NN+i]=v; }
  if (tx==0){ hw[i]=rhw; atomicAdd(sumsq, rhw*rhw); }
}

// ============ K4: Z_ tiles + E block | docs | beta_; zero [18M,25M) ============
__global__ __launch_bounds__(256) void k4_zdoc(const float* __restrict__ HnT,
                      const float* __restrict__ Hh, const float* __restrict__ Hn,
                      const float* __restrict__ hw, const float* __restrict__ sumsq,
                      const int* __restrict__ m_idx, const int* __restrict__ m_cnt,
                      const void* Wmu, const void* bmu, const void* Weta, const void* beta_b,
                      const void* Wgam, const void* bgam, const int* flag,
                      const float* __restrict__ limg,
                      float* __restrict__ out, float* __restrict__ Eblk,
                      uint4* __restrict__ zb){
  int bid=blockIdx.x, tid=threadIdx.x;
  int wi=-1, zi=-1;
  if (bid < 720){ if (bid & 1) zi = bid >> 1; else wi = bid >> 1; }
  else zi = 360 + (bid - 720);
  if (zi >= 0){ zero_span(zb, 18000000L, 7000000L, zi, 1792, tid, 256); return; }
  int b = wi;
  if (b < 256){
    // ---- Z_ tile ----
    int bi=(b&15)*64, bj=(b>>4)*64;
    __shared__ float At[FF*68], Bt[FF*68];
    for (int t=tid;t<FF*64;t+=256){
      int k=t>>6, ii=t&63;
      int gi=bi+ii, gj=bj+ii;
      At[k*68+ii] = (gi<NN)? HnT[k*NN+gi] : 0.f;
      Bt[k*68+ii] = (gj<NN)? HnT[k*NN+gj] : 0.f;
    }
    __syncthreads();
    int tx=tid&15, ty=tid>>4;
    float acc[4][4]={};
    for (int k=0;k<FF;k++){
      float4 av=*(float4*)&At[k*68+4*ty];
      float4 bv=*(float4*)&Bt[k*68+4*tx];
      float aa[4]={av.x,av.y,av.z,av.w};
      float bb[4]={bv.x,bv.y,bv.z,bv.w};
#pragma unroll
      for (int q=0;q<4;q++)
#pragma unroll
        for (int r=0;r<4;r++) acc[q][r]=fmaf(aa[q],bb[r],acc[q][r]);
    }
#pragma unroll
    for (int q=0;q<4;q++){
      int gi=bi+4*ty+q; if (gi>=NN) continue;
      float z[4];
#pragma unroll
      for (int r=0;r<4;r++) z[r]=fmaxf(acc[q][r],0.f);
      int gj0=bj+4*tx;
      if (gj0+3<NN){
        float4 zz; zz.x=z[0]; zz.y=z[1]; zz.z=z[2]; zz.w=z[3];
        *(float4*)&out[O_Z+(size_t)gi*NN+gj0]=zz;
      } else {
        for (int r=0;r<4;r++) if (gj0+r<NN) out[O_Z+(size_t)gi*NN+gj0+r]=z[r];
      }
      if (gi<EB && gj0<EB){
#pragma unroll
        for (int r=0;r<4;r++){
          int gj=gj0+r;
          float t2=2.f-2.f*z[r];
          Eblk[gi*EB+gj]=(gi==gj)?0.f:expf(-t2*t2);
        }
      }
    }
    return;
  }
  if (b >= 356){
    int i=(b-356)*256+tid;
    if (i<NN){
      float rinv=1.f/fmaxf(sqrtf(sumsq[0]),1e-12f);
      out[O_B3+i]=hw[i]*rinv;
    }
    return;
  }
  // ---- doc ----
  int d=b-256;
  int F32 = flag[0];
  __shared__ int sidx[MCAP]; __shared__ float red[4];
  int cnt=m_cnt[d];
  for (int t=tid;t<cnt;t+=256) sidx[t]=m_idx[d*MCAP+t];
  __syncthreads();
  float accH=0.f, accS=0.f;
  if (tid<FF) for (int m=0;m<cnt;m++){ int n=sidx[m]; accH+=Hh[n*FF+tid]; accS+=Hn[n*FF+tid]; }
  float Hp = accH/fmaxf((float)cnt,1.f);
  float pmu = (tid<FF)? Hp*ldf(Wmu, tid, F32)  : 0.f;
  float peta= (tid<FF)? Hp*ldf(Weta, tid, F32) : 0.f;
  float pgam= (tid<FF)? Hp*ldf(Wgam, tid, F32) : 0.f;
  float phw=0.f;
  for (int m=tid;m<cnt;m+=256) phw+=hw[sidx[m]];
  float rmu =blk_red4(pmu,red,tid);
  float reta=blk_red4(peta,red,tid);
  float rgam=blk_red4(pgam,red,tid);
  float rs2 =blk_red4(accS*accS,red,tid);
  float rhw =blk_red4(phw,red,tid);
  if (tid==0){
    float mu =fmaxf(rmu +ldf(bmu,0,F32),   0.f);
    float eta=fmaxf(reta+ldf(beta_b,0,F32),0.f);
    float gam=fmaxf(rgam+ldf(bgam,0,F32),  0.f);
    float Zd =fmaxf(0.5f*(rs2-(float)cnt), 0.f);
    float beta=rhw/fmaxf(sqrtf(sumsq[0]),1e-12f);
    float lt=1.f/(1.f+expf(-(mu+beta+eta*expf(-gam*Zd))));
    out[O_LAM+d]=1.f/(1.f+expf(-(lt+limg[d])));
    out[O_GAM+d]=gam;
    out[O_ETA+d]=eta;
  }
}

// ============ K5: fill nonzero k x k blocks of Z_event ============
__global__ void k5_fill(const float* __restrict__ Eblk, const int* __restrict__ m_cnt,
                        float* __restrict__ outZE){
  int d=blockIdx.x; int k=m_cnt[d]; if (k>EB) k=EB;
  int kk=k*k;
  for (int idx=threadIdx.x; idx<kk; idx+=256){
    int i=idx/k, j=idx-i*k;
    float e=(i==j)?0.f:Eblk[i*EB+j];
    outZE[(size_t)d*1000000 + (size_t)i*1000 + j]=e;
  }
}

extern "C" void kernel_launch(void* const* d_in, const int* in_sizes, int n_in,
                              void* d_out, int out_size, void* d_ws, size_t ws_size,
                              hipStream_t stream) {
  const int* epoch  = (const int*)d_in[0];
  const int* epochs = (const int*)d_in[1];
  const void* A     = d_in[2];
  const void* masks = d_in[3];
  const void* X     = d_in[4];
  const void* img   = d_in[5];
  const void* Wg1   = d_in[6];
  const void* Wg2   = d_in[7];
  const void* Wh1   = d_in[8];
  const void* bh1   = d_in[9];
  const void* Wh2   = d_in[10];
  const void* bh2   = d_in[11];
  const void* Wmu   = d_in[12];
  const void* bmu   = d_in[13];
  const void* Weta  = d_in[14];
  const void* beta_b= d_in[15];
  const void* Wgam  = d_in[16];
  const void* bgam  = d_in[17];
  const void* wm    = d_in[18];
  const void* Wbeta = d_in[19];
  const void* Wm1   = d_in[20];
  const void* bm1   = d_in[21];
  const void* Wm2   = d_in[22];
  const void* bm2   = d_in[23];
  float* out = (float*)d_out;

  float* ws   = (float*)d_ws;
  float* XW   = ws;               // 100000
  float* H1W  = XW  + 100000;
  float* Hh   = H1W + 100000;
  float* Hn   = Hh  + 100000;
  float* HnT  = Hn  + 100000;
  float* Eblk = HnT + 100000;     // 65536
  float* a_val= Eblk+ 65536;      // 96000
  int* a_idx  = (int*)(a_val + 96000); // 96000
  int* a_nnz  = a_idx + 96000;    // 1000
  int* m_idx  = a_nnz + 1000;     // 19200
  int* m_cnt  = m_idx + 19200;    // 100
  float* wpr  = (float*)(m_cnt + 100); // 100
  float* hw   = wpr + 100;        // 1000
  float* sumsq= hw + 1000;        // 4
  int* flag   = (int*)(sumsq + 4); // 4
  float* limg = (float*)(flag + 4); // 128

  uint4* zb = (uint4*)((char*)d_out + (size_t)O_ZE*4); // 16B-aligned, 25M uint4s

  // K1: build + img MLP + XW; zero [0, 8M) interleaved
  hipLaunchKernelGGL(k1_build, dim3(NN+DD+1+DD+NN+2048), dim3(64), 0, stream,
                     A, masks, wm, Wbeta, img, Wm1, bm1, Wm2, bm2, X, Wg1,
                     epoch, epochs,
                     a_idx, a_val, a_nnz, m_idx, m_cnt, wpr, sumsq, limg, flag, XW, zb);
  // K2: H1 + H1W (row-local); zero [8M, 13M) interleaved
  hipLaunchKernelGGL(k2_h1, dim3(NN+1280), dim3(128), 0, stream,
                     XW, Wg2, flag, a_idx, a_val, a_nnz, H1W, zb);
  // K3: H + rowchain (row-local); zero [13M, 18M) interleaved
  hipLaunchKernelGGL(k3_h2, dim3(NN+1280), dim3(128), 0, stream,
                     H1W, a_idx, a_val, a_nnz, Wh1, bh1, Wh2, bh2, wpr, flag,
                     Hh, Hn, HnT, hw, sumsq, out + O_H, zb);
  // K4: Z_ + E | docs | beta_; zero [18M, 25M) interleaved
  hipLaunchKernelGGL(k4_zdoc, dim3(360+1792), dim3(256), 0, stream,
                     HnT, Hh, Hn, hw, sumsq, m_idx, m_cnt,
                     Wmu, bmu, Weta, beta_b, Wgam, bgam, flag, limg,
                     out, Eblk, zb);
  // K5: fill nonzero Z_event blocks (after all zeroing)
  hipLaunchKernelGGL(k5_fill, dim3(DD), dim3(256), 0, stream, Eblk, m_cnt, out + O_ZE);
}

// Round 6
// 576.708 us; speedup vs baseline: 1.6229x; 1.1444x over previous
//
#include <hip/hip_runtime.h>
#include <hip/hip_bf16.h>

typedef __hip_bfloat16 bf;

#define NN   1000
#define DD   100
#define FF   100
#define TIF  512
#define HDD  128
#define EB   256
#define ACAP 96
#define MCAP 192

// output layout (element offsets, float32)
#define O_LAM 0
#define O_Z   100
#define O_B3  1000100
#define O_GAM 1001100
#define O_ETA 1001200
#define O_ZE  1001300
#define O_H   101001300

// dtype-agnostic input load: F32=1 -> buffer is float32, else bf16
__device__ __forceinline__ float ldf(const void* p, int i, int F32){
  return F32 ? ((const float*)p)[i] : __bfloat162float(((const __hip_bfloat16*)p)[i]);
}

// 2-wave (128-thread) block reduction
__device__ __forceinline__ float blk_red(float v, volatile float* red, int tid){
#pragma unroll
  for (int o=32;o>0;o>>=1) v += __shfl_down(v,o,64);
  if ((tid&63)==0) red[tid>>6]=v;
  __syncthreads();
  float r = red[0]+red[1];
  __syncthreads();
  return r;
}
// 4-wave (256-thread) block reduction
__device__ __forceinline__ float blk_red4(float v, volatile float* red, int tid){
#pragma unroll
  for (int o=32;o>0;o>>=1) v += __shfl_down(v,o,64);
  if ((tid&63)==0) red[tid>>6]=v;
  __syncthreads();
  float r = red[0]+red[1]+red[2]+red[3];
  __syncthreads();
  return r;
}

// per-wave dtype sniff over first 512 u16 of X: f32 buffer -> ~12.5% exps >= 0xE0
__device__ __forceinline__ int sniffF32(const unsigned short* __restrict__ p, int tid){
  int lane = tid & 63;
  const ushort4* q = (const ushort4*)p;
  ushort4 a = q[lane*2], b = q[lane*2+1];
  int c = 0;
  c += (((a.x>>7)&0xFF)>=0xE0); c += (((a.y>>7)&0xFF)>=0xE0);
  c += (((a.z>>7)&0xFF)>=0xE0); c += (((a.w>>7)&0xFF)>=0xE0);
  c += (((b.x>>7)&0xFF)>=0xE0); c += (((b.y>>7)&0xFF)>=0xE0);
  c += (((b.z>>7)&0xFF)>=0xE0); c += (((b.w>>7)&0xFF)>=0xE0);
#pragma unroll
  for (int o=32;o>0;o>>=1) c += __shfl_xor(c,o,64);
  return c > 8;
}

// zeroing block zi of nzb handles its chunk of [off, off+cnt) uint4s
// PLAIN stores (same path as the harness fill, which sustains 6.3 TB/s)
__device__ __forceinline__ void zero_span(uint4* __restrict__ zb, long off, long cnt,
                                          int zi, int nzb, int tid, int bdim){
  long per = (cnt + nzb - 1)/nzb;
  long s = (long)zi*per; if (s>cnt) s=cnt;
  long e = s+per; if (e>cnt) e=cnt;
  uint4 z; z.x=z.y=z.z=z.w=0u;
  for (long i=off+s+tid; i<off+e; i+=bdim) zb[i]=z;
}

// ============ K1: build CSR(A), word-lists, wpr, flag, XW; zero [0,8M) ============
// work blocks (2101) and zero blocks (2048) interleaved by blockIdx parity so the
// BW-bound zeroing overlaps the latency-bound compute instead of trailing it.
// (img-MLP moved to K2: it has no K1 dependency and was K1's exposed latency tail.)
__global__ void k1_build(const void* __restrict__ A, const void* __restrict__ masks,
                         const void* __restrict__ wm, const void* __restrict__ Wbeta,
                         const void* __restrict__ X, const void* __restrict__ Wg1,
                         const int* epoch, const int* epochs,
                         int* a_idx, float* a_val, int* a_nnz,
                         int* m_idx, int* m_cnt, float* wpr, float* sumsq,
                         int* flag, float* __restrict__ XW,
                         uint4* __restrict__ zb){
  int bid = blockIdx.x; int lane = threadIdx.x;
  int wi = -1, zi = -1;
  if (bid < 4096){ if (bid & 1) zi = bid >> 1; else wi = bid >> 1; }
  else wi = 2048 + (bid - 4096);
  if (zi >= 0){ zero_span(zb, 0L, 8000000L, zi, 2048, lane, 64); return; }
  int b = wi;  // 0..2100
  int F32 = sniffF32((const unsigned short*)X, lane);
  if (b < NN){
    int i=b, nn=0;
    for (int base=0;base<NN;base+=64){
      int c=base+lane; float v=0.f;
      if (c<NN) v=ldf(A, i*NN+c, F32);
      unsigned long long m=__ballot(v!=0.f);
      if (v!=0.f){
        int pos=nn+__popcll(m&((1ull<<lane)-1ull));
        if (pos<ACAP){ a_idx[i*ACAP+pos]=c; a_val[i*ACAP+pos]=v; }
      }
      nn+=__popcll(m);
    }
    if (lane==0) a_nnz[i]=min(nn,ACAP);
  } else if (b < NN+DD){
    int d=b-NN, nn=0;
    for (int base=0;base<NN;base+=64){
      int c=base+lane; float v=0.f;
      if (c<NN) v=ldf(masks, d*NN+c, F32);
      unsigned long long m=__ballot(v!=0.f);
      if (v!=0.f){
        int pos=nn+__popcll(m&((1ull<<lane)-1ull));
        if (pos<MCAP) m_idx[d*MCAP+pos]=c;
      }
      nn+=__popcll(m);
    }
    if (lane==0) m_cnt[d]=min(nn,MCAP);
  } else if (b == NN+DD){
    __shared__ float w[FF];
    for (int t=lane;t<FF;t+=64) w[t]=ldf(wm, t, F32);
    __syncthreads();
    float sp = 0.3f*(float)epoch[0]/(float)epochs[0];
    int j=(int)lroundf(sp*(float)FF);
    for (int t=lane;t<FF;t+=64){
      float v=w[t]; int r=0;
      for (int u=0;u<FF;u++){ float vu=w[u]; r += ((vu<v)||(vu==v && u<t)) ? 1 : 0; }
      wpr[t] = (r>=j)? ldf(Wbeta, t, F32) : 0.f;
    }
    if (lane==0){ sumsq[0]=0.f; flag[0]=F32; }
  } else {
    // XW row r = X[r] @ Wg1
    int r = b - (NN+DD+1);
    __shared__ float ar[FF];
    for (int t=lane;t<FF;t+=64) ar[t]=ldf(X, r*FF+t, F32);
    __syncthreads();
    for (int col=lane; col<FF; col+=64){
      float a=0.f;
#pragma unroll 4
      for (int c=0;c<FF;c++) a=fmaf(ar[c], ldf(Wg1, c*FF+col, F32), a);
      XW[r*FF+col]=a;
    }
  }
}

// ============ K2: per-row H1=relu(A@XW), H1W=H1@Wg2 | img-MLP; zero [8M,13M) ============
// work: 1000 GCN rows + 100 img-MLP docs (h=tx, 1 h/thread, coalesced Wm1 columns,
// 2 waves TLP — replaces K1's 64-thread 1024-load latency-tail version)
__global__ void k2_h1(const float* __restrict__ XW, const void* __restrict__ Wg2,
                      const int* flag, const int* __restrict__ a_idx,
                      const float* __restrict__ a_val, const int* __restrict__ a_nnz,
                      const void* __restrict__ img, const void* __restrict__ Wm1,
                      const void* __restrict__ bm1, const void* __restrict__ Wm2,
                      const void* __restrict__ bm2, float* __restrict__ limg,
                      float* __restrict__ H1W, uint4* __restrict__ zb){
  int bid=blockIdx.x, tx=threadIdx.x;
  int wi=-1, zi=-1;
  if (bid < 2200){ if (bid & 1) zi = bid >> 1; else wi = bid >> 1; }
  else zi = 1100 + (bid - 2200);
  if (zi >= 0){ zero_span(zb, 8000000L, 5000000L, zi, 1280, tx, 128); return; }
  int row = wi;   // 0..1099
  __shared__ int sidx[ACAP]; __shared__ float sval[ACAP]; __shared__ float t1[FF];
  __shared__ float ir[TIF]; __shared__ float red[2];
  int F32=flag[0];
  if (row < NN){
    int nn=a_nnz[row];
    for (int t=tx;t<nn;t+=128){ sidx[t]=a_idx[row*ACAP+t]; sval[t]=a_val[row*ACAP+t]; }
    __syncthreads();
    if (tx<FF){
      float a=0.f;
      for (int m=0;m<nn;m++) a=fmaf(sval[m], XW[sidx[m]*FF+tx], a);
      t1[tx]=fmaxf(a,0.f);
    }
    __syncthreads();
    if (tx<FF){
      float s=0.f;
#pragma unroll 4
      for (int c=0;c<FF;c++) s=fmaf(t1[c], ldf(Wg2, c*FF+tx, F32), s);
      H1W[row*FF+tx]=s;
    }
  } else {
    // img MLP: limg[d] = MLP(img[d]) pre-sigmoid; h = tx (HDD==128==blockDim)
    int d = row - NN;
    for (int t=tx;t<TIF;t+=128) ir[t]=ldf(img, d*TIF+t, F32);
    __syncthreads();
    float a=ldf(bm1, tx, F32);
#pragma unroll 8
    for (int t=0;t<TIF;t++) a=fmaf(ir[t], ldf(Wm1, t*HDD+tx, F32), a);
    float acc = fmaxf(a,0.f)*ldf(Wm2, tx, F32);
    float r = blk_red(acc, red, tx);
    if (tx==0) limg[d]=r+ldf(bm2,0,F32);
  }
}

// ============ K3: per-row H=A@H1W (+H out), rowchain: Hn/HnT/hw/sumsq; zero [13M,18M) ============
__global__ void k3_h2(const float* __restrict__ H1W, const int* __restrict__ a_idx,
                      const float* __restrict__ a_val, const int* __restrict__ a_nnz,
                      const void* __restrict__ Wh1, const void* __restrict__ bh1,
                      const void* __restrict__ Wh2, const void* __restrict__ bh2,
                      const float* __restrict__ wpr, const int* flag,
                      float* __restrict__ Hh, float* __restrict__ Hn,
                      float* __restrict__ HnT, float* __restrict__ hw, float* sumsq,
                      float* __restrict__ outH, uint4* __restrict__ zb){
  int bid=blockIdx.x, tx=threadIdx.x;
  int wi=-1, zi=-1;
  if (bid < 2000){ if (bid & 1) zi = bid >> 1; else wi = bid >> 1; }
  else zi = 1000 + (bid - 2000);
  if (zi >= 0){ zero_span(zb, 13000000L, 5000000L, zi, 1280, tx, 128); return; }
  int i = wi;
  __shared__ int sidx[ACAP]; __shared__ float sval[ACAP];
  __shared__ float hr[FF], t1[FF];
  __shared__ float red[2];
  int nn=a_nnz[i];
  for (int t=tx;t<nn;t+=128){ sidx[t]=a_idx[i*ACAP+t]; sval[t]=a_val[i*ACAP+t]; }
  __syncthreads();
  if (tx<FF){
    float a=0.f;
    for (int m=0;m<nn;m++) a=fmaf(sval[m], H1W[sidx[m]*FF+tx], a);
    hr[tx]=a; Hh[i*FF+tx]=a; outH[i*FF+tx]=a;
  }
  __syncthreads();
  int F32=flag[0];
  if (tx<FF){
    float a=ldf(bh1, tx, F32);
#pragma unroll 4
    for (int c=0;c<FF;c++) a=fmaf(hr[c], ldf(Wh1, c*FF+tx, F32), a);
    t1[tx]=fmaxf(a,0.f);
  }
  __syncthreads();
  float hel=0.f;
  if (tx<FF){
    float s=ldf(bh2, tx, F32);
#pragma unroll 4
    for (int c=0;c<FF;c++) s=fmaf(t1[c], ldf(Wh2, c*FF+tx, F32), s);
    hel=fmaxf(s,0.f);
  }
  float phw = (tx<FF)? hr[tx]*wpr[tx] : 0.f;
  float rs2 = blk_red(hel*hel, red, tx);
  float rhw = blk_red(phw, red, tx);
  float rinv = 1.f/fmaxf(sqrtf(rs2), 1e-12f);
  if (tx<FF){ float v=hel*rinv; Hn[i*FF+tx]=v; HnT[tx*NN+i]=v; }
  if (tx==0){ hw[i]=rhw; atomicAdd(sumsq, rhw*rhw); }
}

// ============ K4: Z_ tiles + E block | docs | beta_; zero [18M,25M) ============
__global__ __launch_bounds__(256) void k4_zdoc(const float* __restrict__ HnT,
                      const float* __restrict__ Hh, const float* __restrict__ Hn,
                      const float* __restrict__ hw, const float* __restrict__ sumsq,
                      const int* __restrict__ m_idx, const int* __restrict__ m_cnt,
                      const void* Wmu, const void* bmu, const void* Weta, const void* beta_b,
                      const void* Wgam, const void* bgam, const int* flag,
                      const float* __restrict__ limg,
                      float* __restrict__ out, float* __restrict__ Eblk,
                      uint4* __restrict__ zb){
  int bid=blockIdx.x, tid=threadIdx.x;
  int wi=-1, zi=-1;
  if (bid < 720){ if (bid & 1) zi = bid >> 1; else wi = bid >> 1; }
  else zi = 360 + (bid - 720);
  if (zi >= 0){ zero_span(zb, 18000000L, 7000000L, zi, 1792, tid, 256); return; }
  int b = wi;
  if (b < 256){
    // ---- Z_ tile ----
    int bi=(b&15)*64, bj=(b>>4)*64;
    __shared__ float At[FF*68], Bt[FF*68];
    for (int t=tid;t<FF*64;t+=256){
      int k=t>>6, ii=t&63;
      int gi=bi+ii, gj=bj+ii;
      At[k*68+ii] = (gi<NN)? HnT[k*NN+gi] : 0.f;
      Bt[k*68+ii] = (gj<NN)? HnT[k*NN+gj] : 0.f;
    }
    __syncthreads();
    int tx=tid&15, ty=tid>>4;
    float acc[4][4]={};
    for (int k=0;k<FF;k++){
      float4 av=*(float4*)&At[k*68+4*ty];
      float4 bv=*(float4*)&Bt[k*68+4*tx];
      float aa[4]={av.x,av.y,av.z,av.w};
      float bb[4]={bv.x,bv.y,bv.z,bv.w};
#pragma unroll
      for (int q=0;q<4;q++)
#pragma unroll
        for (int r=0;r<4;r++) acc[q][r]=fmaf(aa[q],bb[r],acc[q][r]);
    }
#pragma unroll
    for (int q=0;q<4;q++){
      int gi=bi+4*ty+q; if (gi>=NN) continue;
      float z[4];
#pragma unroll
      for (int r=0;r<4;r++) z[r]=fmaxf(acc[q][r],0.f);
      int gj0=bj+4*tx;
      if (gj0+3<NN){
        float4 zz; zz.x=z[0]; zz.y=z[1]; zz.z=z[2]; zz.w=z[3];
        *(float4*)&out[O_Z+(size_t)gi*NN+gj0]=zz;
      } else {
        for (int r=0;r<4;r++) if (gj0+r<NN) out[O_Z+(size_t)gi*NN+gj0+r]=z[r];
      }
      if (gi<EB && gj0<EB){
#pragma unroll
        for (int r=0;r<4;r++){
          int gj=gj0+r;
          float t2=2.f-2.f*z[r];
          Eblk[gi*EB+gj]=(gi==gj)?0.f:expf(-t2*t2);
        }
      }
    }
    return;
  }
  if (b >= 356){
    int i=(b-356)*256+tid;
    if (i<NN){
      float rinv=1.f/fmaxf(sqrtf(sumsq[0]),1e-12f);
      out[O_B3+i]=hw[i]*rinv;
    }
    return;
  }
  // ---- doc ----
  int d=b-256;
  int F32 = flag[0];
  __shared__ int sidx[MCAP]; __shared__ float red[4];
  int cnt=m_cnt[d];
  for (int t=tid;t<cnt;t+=256) sidx[t]=m_idx[d*MCAP+t];
  __syncthreads();
  float accH=0.f, accS=0.f;
  if (tid<FF) for (int m=0;m<cnt;m++){ int n=sidx[m]; accH+=Hh[n*FF+tid]; accS+=Hn[n*FF+tid]; }
  float Hp = accH/fmaxf((float)cnt,1.f);
  float pmu = (tid<FF)? Hp*ldf(Wmu, tid, F32)  : 0.f;
  float peta= (tid<FF)? Hp*ldf(Weta, tid, F32) : 0.f;
  float pgam= (tid<FF)? Hp*ldf(Wgam, tid, F32) : 0.f;
  float phw=0.f;
  for (int m=tid;m<cnt;m+=256) phw+=hw[sidx[m]];
  float rmu =blk_red4(pmu,red,tid);
  float reta=blk_red4(peta,red,tid);
  float rgam=blk_red4(pgam,red,tid);
  float rs2 =blk_red4(accS*accS,red,tid);
  float rhw =blk_red4(phw,red,tid);
  if (tid==0){
    float mu =fmaxf(rmu +ldf(bmu,0,F32),   0.f);
    float eta=fmaxf(reta+ldf(beta_b,0,F32),0.f);
    float gam=fmaxf(rgam+ldf(bgam,0,F32),  0.f);
    float Zd =fmaxf(0.5f*(rs2-(float)cnt), 0.f);
    float beta=rhw/fmaxf(sqrtf(sumsq[0]),1e-12f);
    float lt=1.f/(1.f+expf(-(mu+beta+eta*expf(-gam*Zd))));
    out[O_LAM+d]=1.f/(1.f+expf(-(lt+limg[d])));
    out[O_GAM+d]=gam;
    out[O_ETA+d]=eta;
  }
}

// ============ K5: fill nonzero k x k blocks of Z_event ============
__global__ void k5_fill(const float* __restrict__ Eblk, const int* __restrict__ m_cnt,
                        float* __restrict__ outZE){
  int d=blockIdx.x; int k=m_cnt[d]; if (k>EB) k=EB;
  int kk=k*k;
  for (int idx=threadIdx.x; idx<kk; idx+=256){
    int i=idx/k, j=idx-i*k;
    float e=(i==j)?0.f:Eblk[i*EB+j];
    outZE[(size_t)d*1000000 + (size_t)i*1000 + j]=e;
  }
}

extern "C" void kernel_launch(void* const* d_in, const int* in_sizes, int n_in,
                              void* d_out, int out_size, void* d_ws, size_t ws_size,
                              hipStream_t stream) {
  const int* epoch  = (const int*)d_in[0];
  const int* epochs = (const int*)d_in[1];
  const void* A     = d_in[2];
  const void* masks = d_in[3];
  const void* X     = d_in[4];
  const void* img   = d_in[5];
  const void* Wg1   = d_in[6];
  const void* Wg2   = d_in[7];
  const void* Wh1   = d_in[8];
  const void* bh1   = d_in[9];
  const void* Wh2   = d_in[10];
  const void* bh2   = d_in[11];
  const void* Wmu   = d_in[12];
  const void* bmu   = d_in[13];
  const void* Weta  = d_in[14];
  const void* beta_b= d_in[15];
  const void* Wgam  = d_in[16];
  const void* bgam  = d_in[17];
  const void* wm    = d_in[18];
  const void* Wbeta = d_in[19];
  const void* Wm1   = d_in[20];
  const void* bm1   = d_in[21];
  const void* Wm2   = d_in[22];
  const void* bm2   = d_in[23];
  float* out = (float*)d_out;

  float* ws   = (float*)d_ws;
  float* XW   = ws;               // 100000
  float* H1W  = XW  + 100000;
  float* Hh   = H1W + 100000;
  float* Hn   = Hh  + 100000;
  float* HnT  = Hn  + 100000;
  float* Eblk = HnT + 100000;     // 65536
  float* a_val= Eblk+ 65536;      // 96000
  int* a_idx  = (int*)(a_val + 96000); // 96000
  int* a_nnz  = a_idx + 96000;    // 1000
  int* m_idx  = a_nnz + 1000;     // 19200
  int* m_cnt  = m_idx + 19200;    // 100
  float* wpr  = (float*)(m_cnt + 100); // 100
  float* hw   = wpr + 100;        // 1000
  float* sumsq= hw + 1000;        // 4
  int* flag   = (int*)(sumsq + 4); // 4
  float* limg = (float*)(flag + 4); // 128

  uint4* zb = (uint4*)((char*)d_out + (size_t)O_ZE*4); // 16B-aligned, 25M uint4s

  // K1: build + XW (2101 work + 2048 zero interleaved); zero [0, 8M)
  hipLaunchKernelGGL(k1_build, dim3(4096+53), dim3(64), 0, stream,
                     A, masks, wm, Wbeta, X, Wg1,
                     epoch, epochs,
                     a_idx, a_val, a_nnz, m_idx, m_cnt, wpr, sumsq, flag, XW, zb);
  // K2: H1+H1W rows | img-MLP (1100 work + 1280 zero interleaved); zero [8M, 13M)
  hipLaunchKernelGGL(k2_h1, dim3(2200+180), dim3(128), 0, stream,
                     XW, Wg2, flag, a_idx, a_val, a_nnz,
                     img, Wm1, bm1, Wm2, bm2, limg, H1W, zb);
  // K3: H + rowchain (row-local); zero [13M, 18M) interleaved
  hipLaunchKernelGGL(k3_h2, dim3(NN+1280), dim3(128), 0, stream,
                     H1W, a_idx, a_val, a_nnz, Wh1, bh1, Wh2, bh2, wpr, flag,
                     Hh, Hn, HnT, hw, sumsq, out + O_H, zb);
  // K4: Z_ + E | docs | beta_; zero [18M, 25M) interleaved
  hipLaunchKernelGGL(k4_zdoc, dim3(360+1792), dim3(256), 0, stream,
                     HnT, Hh, Hn, hw, sumsq, m_idx, m_cnt,
                     Wmu, bmu, Weta, beta_b, Wgam, bgam, flag, limg,
                     out, Eblk, zb);
  // K5: fill nonzero Z_event blocks (after all zeroing)
  hipLaunchKernelGGL(k5_fill, dim3(DD), dim3(256), 0, stream, Eblk, m_cnt, out + O_ZE);
}